// Round 3
// baseline (138.532 us; speedup 1.0000x reference)
//
#include <hip/hip_runtime.h>

typedef unsigned short u16;
typedef __attribute__((ext_vector_type(4))) float  f32x4;
typedef __attribute__((ext_vector_type(8))) short  s16x8;
typedef __attribute__((ext_vector_type(4))) short  s16x4;
typedef __attribute__((ext_vector_type(4))) int    i32x4;

#define MFMA32(a,b,c) __builtin_amdgcn_mfma_f32_16x16x32_bf16((a),(b),(c),0,0,0)

__device__ __forceinline__ short f2bf(float f) {
  unsigned u = __float_as_uint(f);
  u = (u + 0x7fffu + ((u >> 16) & 1u)) >> 16;
  return (short)u;
}
__device__ __forceinline__ unsigned packbf(float lo, float hi) {
  return (unsigned)(u16)f2bf(lo) | ((unsigned)(u16)f2bf(hi) << 16);
}

// Geometry: B=16,T=4096,C=256 -> 256 windows of W=256, H=4, DH=64, RADIUS=32 (33 keys/row)

// ---------------- K0: weight cast + transpose ----------------
__global__ __launch_bounds__(256) void k_prep(const float* __restrict__ wqkv,
                                              const float* __restrict__ wproj,
                                              u16* __restrict__ wqkvT,
                                              u16* __restrict__ wprojT) {
  int idx = blockIdx.x * 256 + threadIdx.x;
  if (idx < 768 * 256) {
    int n = idx >> 8, kk = idx & 255;
    wqkvT[idx] = (u16)f2bf(wqkv[kk * 768 + n]);
  } else {
    int j = idx - 768 * 256;            // 0 .. 65535
    int n = j >> 8, kk = j & 255;
    wprojT[j] = (u16)f2bf(wproj[kk * 256 + n]);
  }
}

// ---------------- K1: qkv = x @ Wqkv  (rows = cw*256, N=768, K=256), bf16 out ----------------
// qkv ws layout: which-blocks (q,k,v) of cw*65536 u16 each; within: w*65536 + h*16384 + row*64 + d
__global__ __launch_bounds__(256) void k_qkv(const float* __restrict__ x,
                                             const u16* __restrict__ wqkvT,
                                             u16* __restrict__ qkvws,
                                             int whichStride) {
  __shared__ u16 As[128][72];   // [m][k], +8 pad
  __shared__ u16 Bs[128][72];   // [n][k] (B^T), +8 pad
  const int tid = threadIdx.x;
  const int lane = tid & 63, wid = tid >> 6;
  const int wm = wid >> 1, wn = wid & 1;
  const int c15 = lane & 15, g = lane >> 4;
  const int Mbase = blockIdx.x * 128;
  const int Nbase = blockIdx.y * 128;

  f32x4 acc[4][4] = {};
  for (int kt = 0; kt < 4; ++kt) {
#pragma unroll
    for (int i = 0; i < 8; ++i) {
      int c = tid + 256 * i;
      int row = c >> 4, ch = c & 15;
      f32x4 v = *(const f32x4*)(x + (size_t)(Mbase + row) * 256 + kt * 64 + ch * 4);
      s16x4 pk; pk[0] = f2bf(v[0]); pk[1] = f2bf(v[1]); pk[2] = f2bf(v[2]); pk[3] = f2bf(v[3]);
      *(s16x4*)&As[row][ch * 4] = pk;
    }
#pragma unroll
    for (int i = 0; i < 4; ++i) {
      int c = tid + 256 * i;
      int row = c >> 3, ch = c & 7;
      i32x4 v = *(const i32x4*)(wqkvT + (size_t)(Nbase + row) * 256 + kt * 64 + ch * 8);
      *(i32x4*)&Bs[row][ch * 8] = v;
    }
    __syncthreads();
#pragma unroll
    for (int ks = 0; ks < 2; ++ks) {
      s16x8 af[4], bf[4];
#pragma unroll
      for (int mt = 0; mt < 4; ++mt) af[mt] = *(const s16x8*)&As[wm * 64 + mt * 16 + c15][ks * 32 + g * 8];
#pragma unroll
      for (int nt = 0; nt < 4; ++nt) bf[nt] = *(const s16x8*)&Bs[wn * 64 + nt * 16 + c15][ks * 32 + g * 8];
#pragma unroll
      for (int mt = 0; mt < 4; ++mt)
#pragma unroll
        for (int nt = 0; nt < 4; ++nt)
          acc[mt][nt] = MFMA32(af[mt], bf[nt], acc[mt][nt]);
    }
    __syncthreads();
  }
#pragma unroll
  for (int nt = 0; nt < 4; ++nt) {
    int n = Nbase + wn * 64 + nt * 16 + c15;
    int which = n >> 8, h = (n >> 6) & 3, dd = n & 63;
    size_t o0 = (size_t)which * whichStride + (size_t)h * 16384 + dd;
#pragma unroll
    for (int mt = 0; mt < 4; ++mt) {
      int m0 = Mbase + wm * 64 + mt * 16 + g * 4;
#pragma unroll
      for (int r = 0; r < 4; ++r) {
        int m = m0 + r;
        int w = m >> 8, rr = m & 255;
        qkvws[o0 + (size_t)w * 65536 + rr * 64] = (u16)f2bf(acc[mt][nt][r]);
      }
    }
  }
}

// ---------------- K2: per-window banded attention + output projection ----------------
__global__ __launch_bounds__(512) void k_attn_proj(const u16* __restrict__ qws,
                                                   const u16* __restrict__ kws,
                                                   const u16* __restrict__ vws,
                                                   const u16* __restrict__ wprojT,
                                                   const float* __restrict__ bias,
                                                   float* __restrict__ out) {
  __shared__ u16 Osh[256 * 256];  // attn output [row][C] bf16, XOR-swizzled, 128 KiB
  const int tid = threadIdx.x;
  const int lane = tid & 63, wid = tid >> 6;
  const int head = wid >> 1, qhalf = wid & 1;
  const int c15 = lane & 15, g = lane >> 4;
  const int win = blockIdx.x;

  const size_t hb = (size_t)(win * 4 + head) * 16384;  // 256*64 per (win,head)
  const u16* Qp = qws + hb;
  const u16* Kp = kws + hb;
  const u16* Vp = vws + hb;
  const int start = qhalf * 8;          // this wave's Q-tiles: [start, start+8); start % 4 == 0

  // 4-slot register rings (slot = jt & 3): K fragments (A-layout) and V fragments (B-layout)
  // 4 slots so the prefetch target (i16+1)&3 never aliases the live s0/s1/s2 slots.
  s16x8 klo[4] = {}, khi[4] = {};
  s16x8 vfr[4][4] = {};

#define LOADKV(jt, slot) do {                                                \
    const u16* _p = Kp + (jt) * 1024 + c15 * 64 + g * 8;                     \
    klo[slot] = *(const s16x8*)_p;                                           \
    khi[slot] = *(const s16x8*)(_p + 32);                                    \
    const int _rb = (jt) * 16 + ((g & 1) << 3);                              \
    _Pragma("unroll")                                                        \
    for (int _dt = 0; _dt < 4; ++_dt) {                                      \
      s16x8 _t;                                                              \
      _Pragma("unroll")                                                      \
      for (int _i = 0; _i < 8; ++_i)                                         \
        _t[_i] = (short)Vp[(_rb + _i) * 64 + _dt * 16 + c15];                \
      vfr[slot][_dt] = _t;                                                   \
    }                                                                        \
  } while (0)

  if (start >= 2) LOADKV(start - 2, 2);   // (start-2)&3 == 2 since start%4==0
  if (start >= 1) LOADKV(start - 1, 3);   // (start-1)&3 == 3
  LOADKV(start, 0);

#pragma unroll
  for (int ii = 0; ii < 8; ++ii) {
    const int i16 = start + ii;
    const int sP = (ii + 1) & 3;   // prefetch slot, distinct from s0/s1/s2 mod 4
    const int s0 = ii & 3;
    const int s1 = (ii + 3) & 3;
    const int s2 = (ii + 2) & 3;
    if (ii < 7) LOADKV(i16 + 1, sP);   // prefetch next K/V tile

    // Q fragments (B-operand of S^T mfma): lane q=c15, k-chunk d=g*8..
    const u16* qp = Qp + i16 * 1024 + c15 * 64 + g * 8;
    const s16x8 qf0 = *(const s16x8*)qp;
    const s16x8 qf1 = *(const s16x8*)(qp + 32);

    // S^T[j][q] = sum_d K[j][d] Q[q][d]; lane holds j = jt*16 + g*4 + r, q = c15
    f32x4 sT0 = {}, sT1 = {}, sT2 = {};
    sT0 = MFMA32(klo[s0], qf0, sT0);
    sT0 = MFMA32(khi[s0], qf1, sT0);
    if (i16 >= 1) { sT1 = MFMA32(klo[s1], qf0, sT1); sT1 = MFMA32(khi[s1], qf1, sT1); }
    if (i16 >= 2) { sT2 = MFMA32(klo[s2], qf0, sT2); sT2 = MFMA32(khi[s2], qf1, sT2); }

    const int qrow = i16 * 16 + c15;
    float e0[4], e1[4], e2[4];
    float vmax = -3.0e38f;
#pragma unroll
    for (int r = 0; r < 4; ++r) {
      int dd = qrow - (i16 * 16 + g * 4 + r);
      e0[r] = (dd >= 0 && dd <= 32) ? sT0[r] * 0.125f : -1.0e30f;
      vmax = fmaxf(vmax, e0[r]);
    }
    if (i16 >= 1) {
#pragma unroll
      for (int r = 0; r < 4; ++r) {
        int dd = qrow - ((i16 - 1) * 16 + g * 4 + r);   // 1..31, always in band
        e1[r] = sT1[r] * 0.125f;
        vmax = fmaxf(vmax, e1[r]);
        (void)dd;
      }
    }
    if (i16 >= 2) {
#pragma unroll
      for (int r = 0; r < 4; ++r) {
        int dd = qrow - ((i16 - 2) * 16 + g * 4 + r);   // 17..47
        e2[r] = (dd <= 32) ? sT2[r] * 0.125f : -1.0e30f;
        vmax = fmaxf(vmax, e2[r]);
      }
    }
    // row-wise reduce across the 4 lane-groups holding this q-row
    vmax = fmaxf(vmax, __shfl_xor(vmax, 16));
    vmax = fmaxf(vmax, __shfl_xor(vmax, 32));
    float ssum = 0.0f;
#pragma unroll
    for (int r = 0; r < 4; ++r) { e0[r] = __expf(e0[r] - vmax); ssum += e0[r]; }
    if (i16 >= 1) {
#pragma unroll
      for (int r = 0; r < 4; ++r) { e1[r] = __expf(e1[r] - vmax); ssum += e1[r]; }
    }
    if (i16 >= 2) {
#pragma unroll
      for (int r = 0; r < 4; ++r) { e2[r] = __expf(e2[r] - vmax); ssum += e2[r]; }
    }
    ssum += __shfl_xor(ssum, 16);
    ssum += __shfl_xor(ssum, 32);
    const float inv = 1.0f / ssum;

    // pack normalized P to bf16 pairs: lane holds P^T[j=g*4+r][q=c15]
    unsigned c0a = packbf(e0[0] * inv, e0[1] * inv), c0b = packbf(e0[2] * inv, e0[3] * inv);
    unsigned c1a = 0, c1b = 0, c2a = 0, c2b = 0;
    if (i16 >= 1) { c1a = packbf(e1[0] * inv, e1[1] * inv); c1b = packbf(e1[2] * inv, e1[3] * inv); }
    if (i16 >= 2) { c2a = packbf(e2[0] * inv, e2[1] * inv); c2b = packbf(e2[2] * inv, e2[3] * inv); }

    // Rebuild A-fragment layout for PV (lane m=q=c15, k=j=g*8+i; zeros for g>=2):
    const int src0 = ((g & 1) << 5) + c15;  // source lane g'=2*(g&1), same q
    const int src1 = src0 + 16;
    const bool alo = (g < 2);
#define MKFRAG(pa, ua, ub) do {                                             \
      int _t0 = __shfl((int)(ua), src0), _t1 = __shfl((int)(ub), src0);     \
      int _t2 = __shfl((int)(ua), src1), _t3 = __shfl((int)(ub), src1);     \
      i32x4 _ti = { alo ? _t0 : 0, alo ? _t1 : 0, alo ? _t2 : 0, alo ? _t3 : 0 }; \
      pa = *(s16x8*)&_ti;                                                   \
    } while (0)
    s16x8 pa0, pa1, pa2;
    MKFRAG(pa0, c0a, c0b);
    MKFRAG(pa1, c1a, c1b);
    MKFRAG(pa2, c2a, c2b);
#undef MKFRAG

    // O[q][d] = sum_j P[q][j] V[j][d]; D: lane holds O[q=g*4+r][d=dt*16+c15]
    f32x4 oa[4] = {};
#pragma unroll
    for (int dt = 0; dt < 4; ++dt) {
      oa[dt] = MFMA32(pa0, vfr[s0][dt], oa[dt]);
      if (i16 >= 1) oa[dt] = MFMA32(pa1, vfr[s1][dt], oa[dt]);
      if (i16 >= 2) oa[dt] = MFMA32(pa2, vfr[s2][dt], oa[dt]);
    }

    // write O tile to LDS (bf16, XOR-swizzled rows)
#pragma unroll
    for (int dt = 0; dt < 4; ++dt) {
#pragma unroll
      for (int r = 0; r < 4; ++r) {
        int row = i16 * 16 + g * 4 + r;
        unsigned addr = (unsigned)(row * 512 + head * 128 + dt * 32 + c15 * 2);
        addr ^= ((unsigned)(row & 7)) << 4;
        *(u16*)((char*)Osh + addr) = (u16)f2bf(oa[dt][r]);
      }
    }
  }
#undef LOADKV

  __syncthreads();

  // projection: out[m][n] = O[m][:] @ Wproj[:][n] + b[n]  (wave owns 32 m-rows)
  s16x8 afr[2][8];
#pragma unroll
  for (int mt = 0; mt < 2; ++mt) {
#pragma unroll
    for (int ks = 0; ks < 8; ++ks) {
      int row = wid * 32 + mt * 16 + c15;
      unsigned addr = ((unsigned)(row * 512 + ks * 64 + g * 16)) ^ (((unsigned)(row & 7)) << 4);
      afr[mt][ks] = *(const s16x8*)((const char*)Osh + addr);
    }
  }
  const int wbase = win * 256;
  for (int nt = 0; nt < 16; ++nt) {
    s16x8 bfr[8];
#pragma unroll
    for (int ks = 0; ks < 8; ++ks)
      bfr[ks] = *(const s16x8*)(wprojT + (nt * 16 + c15) * 256 + ks * 32 + g * 8);
    const float bv = bias[nt * 16 + c15];
    f32x4 a0 = {bv, bv, bv, bv};
    f32x4 a1 = {bv, bv, bv, bv};
#pragma unroll
    for (int ks = 0; ks < 8; ++ks) {
      a0 = MFMA32(afr[0][ks], bfr[ks], a0);
      a1 = MFMA32(afr[1][ks], bfr[ks], a1);
    }
    const int m0 = wbase + wid * 32;
#pragma unroll
    for (int r = 0; r < 4; ++r) {
      out[(size_t)(m0 + g * 4 + r) * 256 + nt * 16 + c15] = a0[r];
      out[(size_t)(m0 + 16 + g * 4 + r) * 256 + nt * 16 + c15] = a1[r];
    }
  }
}

extern "C" void kernel_launch(void* const* d_in, const int* in_sizes, int n_in,
                              void* d_out, int out_size, void* d_ws, size_t ws_size,
                              hipStream_t stream) {
  (void)in_sizes; (void)n_in; (void)out_size;
  const float* x     = (const float*)d_in[0];
  const float* wqkv  = (const float*)d_in[1];
  const float* wproj = (const float*)d_in[2];
  const float* bias  = (const float*)d_in[3];
  float* out = (float*)d_out;
  char* ws = (char*)d_ws;

  // ws layout: [wqkvT 768*256 u16][wprojT 256*256 u16][qkv chunk buffers]
  const size_t wBytes = (size_t)768 * 256 * 2 + (size_t)256 * 256 * 2;  // 524288
  u16* wqkvT  = (u16*)ws;
  u16* wprojT = (u16*)(ws + (size_t)768 * 256 * 2);
  u16* qkvbuf = (u16*)(ws + wBytes);

  // per-window qkv bytes: 3 * 256 rows * 256 ch * 2B = 393216
  const size_t perWin = 393216;
  size_t avail = (ws_size > wBytes) ? (ws_size - wBytes) : 0;
  int cwMax = (int)(avail / perWin);
  if (cwMax < 1) return;               // cannot run without scratch
  if (cwMax > 256) cwMax = 256;

  k_prep<<<1024, 256, 0, stream>>>(wqkv, wproj, wqkvT, wprojT);

  for (int w0 = 0; w0 < 256; w0 += cwMax) {
    int cw = 256 - w0 < cwMax ? 256 - w0 : cwMax;
    int whichStride = cw * 65536;      // u16 elements per which-block (q/k/v)
    k_qkv<<<dim3(cw * 2, 6), 256, 0, stream>>>(x + (size_t)w0 * 65536, wqkvT, qkvbuf, whichStride);
    k_attn_proj<<<cw, 512, 0, stream>>>(qkvbuf,
                                        qkvbuf + (size_t)whichStride,
                                        qkvbuf + (size_t)2 * whichStride,
                                        wprojT, bias,
                                        out + (size_t)w0 * 65536);
  }
}

// Round 6
// 111.453 us; speedup vs baseline: 1.2430x; 1.2430x over previous
//
#include <hip/hip_runtime.h>
#include <hip/hip_bf16.h>

typedef unsigned short u16;
typedef __attribute__((ext_vector_type(4))) float  f32x4;
typedef __attribute__((ext_vector_type(8))) short  s16x8;
typedef __attribute__((ext_vector_type(4))) short  s16x4;
typedef __attribute__((ext_vector_type(4))) int    i32x4;
typedef __attribute__((ext_vector_type(2))) unsigned int u32x2;

#define MFMA32(a,b,c) __builtin_amdgcn_mfma_f32_16x16x32_bf16((a),(b),(c),0,0,0)

__device__ __forceinline__ short f2bf(float f) {
  unsigned u = __float_as_uint(f);
  u = (u + 0x7fffu + ((u >> 16) & 1u)) >> 16;
  return (short)u;
}
__device__ __forceinline__ unsigned packbf(float lo, float hi) {
  return (unsigned)(u16)f2bf(lo) | ((unsigned)(u16)f2bf(hi) << 16);
}
// packed RNE f32x2 -> bf16x2 (v_cvt_pk_bf16_f32)
__device__ __forceinline__ unsigned cvtpk(float a, float b) {
  float2 f; f.x = a; f.y = b;
  __hip_bfloat162 h = __float22bfloat162_rn(f);
  unsigned u; __builtin_memcpy(&u, &h, 4); return u;
}

// Geometry: B=16,T=4096,C=256 -> 256 windows of W=256, H=4, DH=64, RADIUS=32 (33 keys/row)

// ---------------- K0: weight cast + transpose ----------------
__global__ __launch_bounds__(256) void k_prep(const float* __restrict__ wqkv,
                                              const float* __restrict__ wproj,
                                              u16* __restrict__ wqkvT,
                                              u16* __restrict__ wprojT) {
  int idx = blockIdx.x * 256 + threadIdx.x;
  if (idx < 768 * 256) {
    int n = idx >> 8, kk = idx & 255;
    wqkvT[idx] = (u16)f2bf(wqkv[kk * 768 + n]);
  } else {
    int j = idx - 768 * 256;            // 0 .. 65535
    int n = j >> 8, kk = j & 255;
    wprojT[j] = (u16)f2bf(wproj[kk * 256 + n]);
  }
}

// ---------------- K1: qkv = x @ Wqkv  (rows = nm*128, N=768, K=256), bf16 out ----------------
// 2-phase pipelined, LDS double-buffered, XCD-aware grid (x-tile L2 reuse across the 6 N-blocks).
__global__ __launch_bounds__(256) void k_qkv(const float* __restrict__ x,
                                             const u16* __restrict__ wqkvT,
                                             u16* __restrict__ qkvws,
                                             int whichStride, int nmTiles) {
  __shared__ u16 As[2][128][72];   // [m][k] bf16, +8 pad
  __shared__ u16 Bs[2][8192];      // [n][k] bf16, XOR-swizzled linear (row*64+k)
  const int tid = threadIdx.x;
  const int lane = tid & 63, wid = tid >> 6;
  const int wm = wid >> 1, wn = wid & 1;
  const int c15 = lane & 15, g = lane >> 4;

  // grid mapping: per-XCD contiguous m-range, n-fastest -> 6 N-blocks of same x-tile
  // run consecutively on the same XCD (L2 reuse). Bijective iff nmTiles % 8 == 0.
  int s = blockIdx.x, m, nIdx;
  if ((nmTiles & 7) == 0) {
    int xcd = s & 7, t = s >> 3, mPerX = nmTiles >> 3;
    int lm = t / 6; nIdx = t - lm * 6; m = xcd * mPerX + lm;
  } else { m = s / 6; nIdx = s - (s / 6) * 6; }
  const size_t Mbase = (size_t)m * 128;
  const int Nbase = nIdx * 128;

#define LOADX(kt, xa) do {                                                      \
    _Pragma("unroll")                                                           \
    for (int _i = 0; _i < 8; ++_i) {                                            \
      int _c = tid + 256 * _i, _row = _c >> 4, _ch = _c & 15;                   \
      xa[_i] = *(const f32x4*)(x + (Mbase + _row) * 256 + (kt) * 64 + _ch * 4); \
    } } while (0)
#define LOADB(kt, ba) do {                                                      \
    _Pragma("unroll")                                                           \
    for (int _i = 0; _i < 4; ++_i) {                                            \
      int _c = tid + 256 * _i, _row = _c >> 3, _ch = _c & 7;                    \
      ba[_i] = *(const i32x4*)(wqkvT + (size_t)(Nbase + _row) * 256 + (kt) * 64 + _ch * 8); \
    } } while (0)
#define STAGE(kt, xa, ba) do {                                                  \
    _Pragma("unroll")                                                           \
    for (int _i = 0; _i < 8; ++_i) {                                            \
      int _c = tid + 256 * _i, _row = _c >> 4, _ch = _c & 15;                   \
      u32x2 _p = { cvtpk(xa[_i][0], xa[_i][1]), cvtpk(xa[_i][2], xa[_i][3]) };  \
      *(u32x2*)&As[(kt) & 1][_row][_ch * 4] = _p;                               \
    }                                                                           \
    _Pragma("unroll")                                                           \
    for (int _i = 0; _i < 4; ++_i) {                                            \
      int _c = tid + 256 * _i, _row = _c >> 3, _ch = _c & 7;                    \
      unsigned _b = (unsigned)(_row * 128 + _ch * 16) ^ (((unsigned)(_row & 7)) << 4); \
      *(i32x4*)((char*)Bs[(kt) & 1] + _b) = ba[_i];                             \
    } } while (0)
#define COMPUTE(kt) do {                                                        \
    _Pragma("unroll")                                                           \
    for (int _ks = 0; _ks < 2; ++_ks) {                                         \
      s16x8 _af[4], _bf[4];                                                     \
      _Pragma("unroll")                                                         \
      for (int _mt = 0; _mt < 4; ++_mt)                                         \
        _af[_mt] = *(const s16x8*)&As[(kt) & 1][wm * 64 + _mt * 16 + c15][_ks * 32 + g * 8]; \
      _Pragma("unroll")                                                         \
      for (int _nt = 0; _nt < 4; ++_nt) {                                       \
        int _row = wn * 64 + _nt * 16 + c15;                                    \
        unsigned _b = (unsigned)(_row * 128 + _ks * 64 + g * 16) ^ (((unsigned)(_row & 7)) << 4); \
        _bf[_nt] = *(const s16x8*)((const char*)Bs[(kt) & 1] + _b);             \
      }                                                                         \
      _Pragma("unroll")                                                         \
      for (int _mt = 0; _mt < 4; ++_mt)                                         \
        _Pragma("unroll")                                                       \
        for (int _nt = 0; _nt < 4; ++_nt)                                       \
          acc[_mt][_nt] = MFMA32(_af[_mt], _bf[_nt], acc[_mt][_nt]);            \
    } } while (0)

  f32x4 acc[4][4] = {};
  f32x4 xr[8], xr2[8];
  i32x4 br[4], br2[4];

  LOADX(0, xr); LOADB(0, br);
  STAGE(0, xr, br);
  __syncthreads();
  LOADX(1, xr2); LOADB(1, br2);   // in flight during COMPUTE(0)
  COMPUTE(0);
  STAGE(1, xr2, br2);
  __syncthreads();
  LOADX(2, xr); LOADB(2, br);
  COMPUTE(1);
  STAGE(2, xr, br);
  __syncthreads();
  LOADX(3, xr2); LOADB(3, br2);
  COMPUTE(2);
  STAGE(3, xr2, br2);
  __syncthreads();
  COMPUTE(3);

#undef LOADX
#undef LOADB
#undef STAGE
#undef COMPUTE

  // store: n -> (which,h,d); m -> (window,row)
#pragma unroll
  for (int nt = 0; nt < 4; ++nt) {
    int n = Nbase + wn * 64 + nt * 16 + c15;
    int which = n >> 8, h = (n >> 6) & 3, dd = n & 63;
    size_t o0 = (size_t)which * whichStride + (size_t)h * 16384 + dd;
#pragma unroll
    for (int mt = 0; mt < 4; ++mt) {
      size_t m0 = Mbase + wm * 64 + mt * 16 + g * 4;
#pragma unroll
      for (int rp = 0; rp < 2; ++rp) {
        unsigned u = cvtpk(acc[mt][nt][rp * 2], acc[mt][nt][rp * 2 + 1]);
        size_t ma = m0 + rp * 2, mb = ma + 1;
        qkvws[o0 + (ma >> 8) * 65536 + (ma & 255) * 64] = (u16)u;
        qkvws[o0 + (mb >> 8) * 65536 + (mb & 255) * 64] = (u16)(u >> 16);
      }
    }
  }
}

// ---------------- K2: per-window banded attention + output projection ----------------
__global__ __launch_bounds__(512) void k_attn_proj(const u16* __restrict__ qws,
                                                   const u16* __restrict__ kws,
                                                   const u16* __restrict__ vws,
                                                   const u16* __restrict__ wprojT,
                                                   const float* __restrict__ bias,
                                                   float* __restrict__ out) {
  __shared__ u16 Osh[256 * 256];  // attn output [row][C] bf16, XOR-swizzled, 128 KiB
  const int tid = threadIdx.x;
  const int lane = tid & 63, wid = tid >> 6;
  const int head = wid >> 1, qhalf = wid & 1;
  const int c15 = lane & 15, g = lane >> 4;
  const int win = blockIdx.x;

  const size_t hb = (size_t)(win * 4 + head) * 16384;  // 256*64 per (win,head)
  const u16* Qp = qws + hb;
  const u16* Kp = kws + hb;
  const u16* Vp = vws + hb;
  const int start = qhalf * 8;          // this wave's Q-tiles: [start, start+8); start % 4 == 0

  // 4-slot register rings (slot = jt & 3): K fragments (A-layout) and V fragments (B-layout)
  s16x8 klo[4] = {}, khi[4] = {};
  s16x8 vfr[4][4] = {};

#define LOADKV(jt, slot) do {                                                \
    const u16* _p = Kp + (jt) * 1024 + c15 * 64 + g * 8;                     \
    klo[slot] = *(const s16x8*)_p;                                           \
    khi[slot] = *(const s16x8*)(_p + 32);                                    \
    const int _rb = (jt) * 16 + ((g & 1) << 3);                              \
    _Pragma("unroll")                                                        \
    for (int _dt = 0; _dt < 4; ++_dt) {                                      \
      s16x8 _t;                                                              \
      _Pragma("unroll")                                                      \
      for (int _i = 0; _i < 8; ++_i)                                         \
        _t[_i] = (short)Vp[(_rb + _i) * 64 + _dt * 16 + c15];                \
      vfr[slot][_dt] = _t;                                                   \
    }                                                                        \
  } while (0)

  if (start >= 2) LOADKV(start - 2, 2);
  if (start >= 1) LOADKV(start - 1, 3);
  LOADKV(start, 0);

#pragma unroll
  for (int ii = 0; ii < 8; ++ii) {
    const int i16 = start + ii;
    const int sP = (ii + 1) & 3;
    const int s0 = ii & 3;
    const int s1 = (ii + 3) & 3;
    const int s2 = (ii + 2) & 3;
    if (ii < 7) LOADKV(i16 + 1, sP);   // prefetch next K/V tile

    const u16* qp = Qp + i16 * 1024 + c15 * 64 + g * 8;
    const s16x8 qf0 = *(const s16x8*)qp;
    const s16x8 qf1 = *(const s16x8*)(qp + 32);

    // S^T[j][q] = sum_d K[j][d] Q[q][d]; lane holds j = jt*16 + g*4 + r, q = c15
    f32x4 sT0 = {}, sT1 = {}, sT2 = {};
    sT0 = MFMA32(klo[s0], qf0, sT0);
    sT0 = MFMA32(khi[s0], qf1, sT0);
    if (i16 >= 1) { sT1 = MFMA32(klo[s1], qf0, sT1); sT1 = MFMA32(khi[s1], qf1, sT1); }
    if (i16 >= 2) { sT2 = MFMA32(klo[s2], qf0, sT2); sT2 = MFMA32(khi[s2], qf1, sT2); }

    const int qrow = i16 * 16 + c15;
    float e0[4], e1[4], e2[4];
    float vmax = -3.0e38f;
#pragma unroll
    for (int r = 0; r < 4; ++r) {
      int dd = qrow - (i16 * 16 + g * 4 + r);
      e0[r] = (dd >= 0 && dd <= 32) ? sT0[r] * 0.125f : -1.0e30f;
      vmax = fmaxf(vmax, e0[r]);
    }
    if (i16 >= 1) {
#pragma unroll
      for (int r = 0; r < 4; ++r) {           // dd in 1..31, always in band
        e1[r] = sT1[r] * 0.125f;
        vmax = fmaxf(vmax, e1[r]);
      }
    }
    if (i16 >= 2) {
#pragma unroll
      for (int r = 0; r < 4; ++r) {
        int dd = qrow - ((i16 - 2) * 16 + g * 4 + r);   // 17..47
        e2[r] = (dd <= 32) ? sT2[r] * 0.125f : -1.0e30f;
        vmax = fmaxf(vmax, e2[r]);
      }
    }
    vmax = fmaxf(vmax, __shfl_xor(vmax, 16));
    vmax = fmaxf(vmax, __shfl_xor(vmax, 32));
    float ssum = 0.0f;
#pragma unroll
    for (int r = 0; r < 4; ++r) { e0[r] = __expf(e0[r] - vmax); ssum += e0[r]; }
    if (i16 >= 1) {
#pragma unroll
      for (int r = 0; r < 4; ++r) { e1[r] = __expf(e1[r] - vmax); ssum += e1[r]; }
    }
    if (i16 >= 2) {
#pragma unroll
      for (int r = 0; r < 4; ++r) { e2[r] = __expf(e2[r] - vmax); ssum += e2[r]; }
    }
    ssum += __shfl_xor(ssum, 16);
    ssum += __shfl_xor(ssum, 32);
    const float inv = 1.0f / ssum;

    unsigned c0a = packbf(e0[0] * inv, e0[1] * inv), c0b = packbf(e0[2] * inv, e0[3] * inv);
    unsigned c1a = 0, c1b = 0, c2a = 0, c2b = 0;
    if (i16 >= 1) { c1a = packbf(e1[0] * inv, e1[1] * inv); c1b = packbf(e1[2] * inv, e1[3] * inv); }
    if (i16 >= 2) { c2a = packbf(e2[0] * inv, e2[1] * inv); c2b = packbf(e2[2] * inv, e2[3] * inv); }

    const int src0 = ((g & 1) << 5) + c15;
    const int src1 = src0 + 16;
    const bool alo = (g < 2);
#define MKFRAG(pa, ua, ub) do {                                             \
      int _t0 = __shfl((int)(ua), src0), _t1 = __shfl((int)(ub), src0);     \
      int _t2 = __shfl((int)(ua), src1), _t3 = __shfl((int)(ub), src1);     \
      i32x4 _ti = { alo ? _t0 : 0, alo ? _t1 : 0, alo ? _t2 : 0, alo ? _t3 : 0 }; \
      pa = *(s16x8*)&_ti;                                                   \
    } while (0)
    s16x8 pa0, pa1, pa2;
    MKFRAG(pa0, c0a, c0b);
    MKFRAG(pa1, c1a, c1b);
    MKFRAG(pa2, c2a, c2b);
#undef MKFRAG

    f32x4 oa[4] = {};
#pragma unroll
    for (int dt = 0; dt < 4; ++dt) {
      oa[dt] = MFMA32(pa0, vfr[s0][dt], oa[dt]);
      if (i16 >= 1) oa[dt] = MFMA32(pa1, vfr[s1][dt], oa[dt]);
      if (i16 >= 2) oa[dt] = MFMA32(pa2, vfr[s2][dt], oa[dt]);
    }

#pragma unroll
    for (int dt = 0; dt < 4; ++dt) {
#pragma unroll
      for (int r = 0; r < 4; ++r) {
        int row = i16 * 16 + g * 4 + r;
        unsigned addr = (unsigned)(row * 512 + head * 128 + dt * 32 + c15 * 2);
        addr ^= ((unsigned)(row & 7)) << 4;
        *(u16*)((char*)Osh + addr) = (u16)f2bf(oa[dt][r]);
      }
    }
  }
#undef LOADKV

  __syncthreads();

  s16x8 afr[2][8];
#pragma unroll
  for (int mt = 0; mt < 2; ++mt) {
#pragma unroll
    for (int ks = 0; ks < 8; ++ks) {
      int row = wid * 32 + mt * 16 + c15;
      unsigned addr = ((unsigned)(row * 512 + ks * 64 + g * 16)) ^ (((unsigned)(row & 7)) << 4);
      afr[mt][ks] = *(const s16x8*)((const char*)Osh + addr);
    }
  }
  const int wbase = win * 256;
  for (int nt = 0; nt < 16; ++nt) {
    s16x8 bfr[8];
#pragma unroll
    for (int ks = 0; ks < 8; ++ks)
      bfr[ks] = *(const s16x8*)(wprojT + (nt * 16 + c15) * 256 + ks * 32 + g * 8);
    const float bv = bias[nt * 16 + c15];
    f32x4 a0 = {bv, bv, bv, bv};
    f32x4 a1 = {bv, bv, bv, bv};
#pragma unroll
    for (int ks = 0; ks < 8; ++ks) {
      a0 = MFMA32(afr[0][ks], bfr[ks], a0);
      a1 = MFMA32(afr[1][ks], bfr[ks], a1);
    }
    const int m0 = wbase + wid * 32;
#pragma unroll
    for (int r = 0; r < 4; ++r) {
      out[(size_t)(m0 + g * 4 + r) * 256 + nt * 16 + c15] = a0[r];
      out[(size_t)(m0 + 16 + g * 4 + r) * 256 + nt * 16 + c15] = a1[r];
    }
  }
}

extern "C" void kernel_launch(void* const* d_in, const int* in_sizes, int n_in,
                              void* d_out, int out_size, void* d_ws, size_t ws_size,
                              hipStream_t stream) {
  (void)in_sizes; (void)n_in; (void)out_size;
  const float* x     = (const float*)d_in[0];
  const float* wqkv  = (const float*)d_in[1];
  const float* wproj = (const float*)d_in[2];
  const float* bias  = (const float*)d_in[3];
  float* out = (float*)d_out;
  char* ws = (char*)d_ws;

  const size_t wBytes = (size_t)768 * 256 * 2 + (size_t)256 * 256 * 2;  // 524288
  u16* wqkvT  = (u16*)ws;
  u16* wprojT = (u16*)(ws + (size_t)768 * 256 * 2);
  u16* qkvbuf = (u16*)(ws + wBytes);

  const size_t perWin = 393216;        // 3 * 256 * 256 * 2 B
  size_t avail = (ws_size > wBytes) ? (ws_size - wBytes) : 0;
  int cwMax = (int)(avail / perWin);
  if (cwMax < 1) return;
  if (cwMax > 256) cwMax = 256;
  if (cwMax >= 4) cwMax &= ~3;         // keep nmTiles % 8 == 0 for the XCD mapping

  k_prep<<<1024, 256, 0, stream>>>(wqkv, wproj, wqkvT, wprojT);

  for (int w0 = 0; w0 < 256; w0 += cwMax) {
    int cw = 256 - w0 < cwMax ? 256 - w0 : cwMax;
    int whichStride = cw * 65536;
    int nm = cw * 2;                   // 128-row M-tiles
    k_qkv<<<nm * 6, 256, 0, stream>>>(x + (size_t)w0 * 65536, wqkvT, qkvbuf, whichStride, nm);
    k_attn_proj<<<cw, 512, 0, stream>>>(qkvbuf,
                                        qkvbuf + (size_t)whichStride,
                                        qkvbuf + (size_t)2 * whichStride,
                                        wprojT, bias,
                                        out + (size_t)w0 * 65536);
  }
}

// Round 7
// 110.367 us; speedup vs baseline: 1.2552x; 1.0098x over previous
//
#include <hip/hip_runtime.h>
#include <hip/hip_bf16.h>

typedef unsigned short u16;
typedef __attribute__((ext_vector_type(4))) float  f32x4;
typedef __attribute__((ext_vector_type(8))) short  s16x8;
typedef __attribute__((ext_vector_type(4))) short  s16x4;
typedef __attribute__((ext_vector_type(4))) int    i32x4;
typedef __attribute__((ext_vector_type(2))) unsigned int u32x2;

#define MFMA32(a,b,c) __builtin_amdgcn_mfma_f32_16x16x32_bf16((a),(b),(c),0,0,0)

__device__ __forceinline__ short f2bf(float f) {
  unsigned u = __float_as_uint(f);
  u = (u + 0x7fffu + ((u >> 16) & 1u)) >> 16;
  return (short)u;
}
__device__ __forceinline__ unsigned packbf(float lo, float hi) {
  return (unsigned)(u16)f2bf(lo) | ((unsigned)(u16)f2bf(hi) << 16);
}
// packed RNE f32x2 -> bf16x2 (v_cvt_pk_bf16_f32)
__device__ __forceinline__ unsigned cvtpk(float a, float b) {
  float2 f; f.x = a; f.y = b;
  __hip_bfloat162 h = __float22bfloat162_rn(f);
  unsigned u; __builtin_memcpy(&u, &h, 4); return u;
}

// Geometry: B=16,T=4096,C=256 -> 256 windows of W=256, H=4, DH=64, RADIUS=32 (33 keys/row)

// ---------------- K0: weight cast + transpose ----------------
__global__ __launch_bounds__(256) void k_prep(const float* __restrict__ wqkv,
                                              const float* __restrict__ wproj,
                                              u16* __restrict__ wqkvT,
                                              u16* __restrict__ wprojT) {
  int idx = blockIdx.x * 256 + threadIdx.x;
  if (idx < 768 * 256) {
    int n = idx >> 8, kk = idx & 255;
    wqkvT[idx] = (u16)f2bf(wqkv[kk * 768 + n]);
  } else {
    int j = idx - 768 * 256;            // 0 .. 65535
    int n = j >> 8, kk = j & 255;
    wprojT[j] = (u16)f2bf(wproj[kk * 256 + n]);
  }
}

// ---------------- K1: qkv = x @ Wqkv  (rows = nm*128, N=768, K=256), bf16 out ----------------
// 2-phase pipelined, LDS double-buffered, XCD-aware grid, LDS-transposed coalesced epilogue.
__global__ __launch_bounds__(256) void k_qkv(const float* __restrict__ x,
                                             const u16* __restrict__ wqkvT,
                                             u16* __restrict__ qkvws,
                                             int whichStride, int nmTiles) {
  __shared__ u16 As[2][128][72];   // [m][k] bf16, +8 pad (36864 B; reused as C-tile in epilogue)
  __shared__ u16 Bs[2][8192];      // [n][k] bf16, XOR-swizzled linear
  const int tid = threadIdx.x;
  const int lane = tid & 63, wid = tid >> 6;
  const int wm = wid >> 1, wn = wid & 1;
  const int c15 = lane & 15, g = lane >> 4;

  // grid mapping: per-XCD contiguous m-range, n-fastest -> 6 N-blocks of same x-tile
  // run consecutively on the same XCD (L2 reuse). Bijective iff nmTiles % 8 == 0.
  int s = blockIdx.x, m, nIdx;
  if ((nmTiles & 7) == 0) {
    int xcd = s & 7, t = s >> 3, mPerX = nmTiles >> 3;
    int lm = t / 6; nIdx = t - lm * 6; m = xcd * mPerX + lm;
  } else { m = s / 6; nIdx = s - (s / 6) * 6; }
  const size_t Mbase = (size_t)m * 128;
  const int Nbase = nIdx * 128;

#define LOADX(kt, xa) do {                                                      \
    _Pragma("unroll")                                                           \
    for (int _i = 0; _i < 8; ++_i) {                                            \
      int _c = tid + 256 * _i, _row = _c >> 4, _ch = _c & 15;                   \
      xa[_i] = *(const f32x4*)(x + (Mbase + _row) * 256 + (kt) * 64 + _ch * 4); \
    } } while (0)
#define LOADB(kt, ba) do {                                                      \
    _Pragma("unroll")                                                           \
    for (int _i = 0; _i < 4; ++_i) {                                            \
      int _c = tid + 256 * _i, _row = _c >> 3, _ch = _c & 7;                    \
      ba[_i] = *(const i32x4*)(wqkvT + (size_t)(Nbase + _row) * 256 + (kt) * 64 + _ch * 8); \
    } } while (0)
#define STAGE(kt, xa, ba) do {                                                  \
    _Pragma("unroll")                                                           \
    for (int _i = 0; _i < 8; ++_i) {                                            \
      int _c = tid + 256 * _i, _row = _c >> 4, _ch = _c & 15;                   \
      u32x2 _p = { cvtpk(xa[_i][0], xa[_i][1]), cvtpk(xa[_i][2], xa[_i][3]) };  \
      *(u32x2*)&As[(kt) & 1][_row][_ch * 4] = _p;                               \
    }                                                                           \
    _Pragma("unroll")                                                           \
    for (int _i = 0; _i < 4; ++_i) {                                            \
      int _c = tid + 256 * _i, _row = _c >> 3, _ch = _c & 7;                    \
      unsigned _b = (unsigned)(_row * 128 + _ch * 16) ^ (((unsigned)(_row & 7)) << 4); \
      *(i32x4*)((char*)Bs[(kt) & 1] + _b) = ba[_i];                             \
    } } while (0)
#define COMPUTE(kt) do {                                                        \
    _Pragma("unroll")                                                           \
    for (int _ks = 0; _ks < 2; ++_ks) {                                         \
      s16x8 _af[4], _bf[4];                                                     \
      _Pragma("unroll")                                                         \
      for (int _mt = 0; _mt < 4; ++_mt)                                         \
        _af[_mt] = *(const s16x8*)&As[(kt) & 1][wm * 64 + _mt * 16 + c15][_ks * 32 + g * 8]; \
      _Pragma("unroll")                                                         \
      for (int _nt = 0; _nt < 4; ++_nt) {                                       \
        int _row = wn * 64 + _nt * 16 + c15;                                    \
        unsigned _b = (unsigned)(_row * 128 + _ks * 64 + g * 16) ^ (((unsigned)(_row & 7)) << 4); \
        _bf[_nt] = *(const s16x8*)((const char*)Bs[(kt) & 1] + _b);             \
      }                                                                         \
      _Pragma("unroll")                                                         \
      for (int _mt = 0; _mt < 4; ++_mt)                                         \
        _Pragma("unroll")                                                       \
        for (int _nt = 0; _nt < 4; ++_nt)                                       \
          acc[_mt][_nt] = MFMA32(_af[_mt], _bf[_nt], acc[_mt][_nt]);            \
    } } while (0)

  f32x4 acc[4][4] = {};
  f32x4 xr[8], xr2[8];
  i32x4 br[4], br2[4];

  LOADX(0, xr); LOADB(0, br);
  STAGE(0, xr, br);
  __syncthreads();
  LOADX(1, xr2); LOADB(1, br2);   // in flight during COMPUTE(0)
  COMPUTE(0);
  STAGE(1, xr2, br2);
  __syncthreads();
  LOADX(2, xr); LOADB(2, br);
  COMPUTE(1);
  STAGE(2, xr, br);
  __syncthreads();
  LOADX(3, xr2); LOADB(3, br2);
  COMPUTE(2);
  STAGE(3, xr2, br2);
  __syncthreads();
  COMPUTE(3);

#undef LOADX
#undef LOADB
#undef STAGE
#undef COMPUTE

  // ---- epilogue: acc -> LDS [m][n] bf16 -> coalesced 16B/lane global stores ----
  __syncthreads();                       // all LDS reads of COMPUTE(3) done
  u16* Csh = &As[0][0][0];               // 32768 B needed, 36864 B available

  // write C tile: m = wm*64+mt*16+g*4+r, n = wn*64+nt*16+c15; swizzle ^(m&7)<<4 (2-way max)
#pragma unroll
  for (int mt = 0; mt < 4; ++mt)
#pragma unroll
    for (int nt = 0; nt < 4; ++nt)
#pragma unroll
      for (int r = 0; r < 4; ++r) {
        int mm = wm * 64 + mt * 16 + g * 4 + r;
        int nn = wn * 64 + nt * 16 + c15;
        unsigned addr = (unsigned)(mm * 256 + nn * 2) ^ (((unsigned)(mm & 7)) << 4);
        *(u16*)((char*)Csh + addr) = (u16)f2bf(acc[mt][nt][r]);
      }
  __syncthreads();

  // read back row-major (16 lanes per row, 16B chunks) and store contiguous dwordx4
#pragma unroll
  for (int i = 0; i < 8; ++i) {
    int c = tid + 256 * i;               // 0..2047 chunk id (16B each)
    int mm = c >> 4;                     // 0..127
    int n0 = (c & 15) * 8;               // 0..120, never straddles a 64-d group
    unsigned addr = (unsigned)(mm * 256 + n0 * 2) ^ (((unsigned)(mm & 7)) << 4);
    i32x4 v = *(const i32x4*)((const char*)Csh + addr);
    int ng = Nbase + n0;
    int which = ng >> 8, h = (ng >> 6) & 3, dd = ng & 63;
    size_t mg = Mbase + mm;
    size_t o = (size_t)which * whichStride + (size_t)h * 16384
             + (mg >> 8) * 65536 + (mg & 255) * 64 + dd;
    *(i32x4*)(qkvws + o) = v;
  }
}

// ---------------- K2: per-window banded attention + output projection ----------------
__global__ __launch_bounds__(512) void k_attn_proj(const u16* __restrict__ qws,
                                                   const u16* __restrict__ kws,
                                                   const u16* __restrict__ vws,
                                                   const u16* __restrict__ wprojT,
                                                   const float* __restrict__ bias,
                                                   float* __restrict__ out) {
  __shared__ u16 Osh[256 * 256];  // attn output [row][C] bf16, XOR-swizzled, 128 KiB
  const int tid = threadIdx.x;
  const int lane = tid & 63, wid = tid >> 6;
  const int head = wid >> 1, qhalf = wid & 1;
  const int c15 = lane & 15, g = lane >> 4;
  const int win = blockIdx.x;

  const size_t hb = (size_t)(win * 4 + head) * 16384;  // 256*64 per (win,head)
  const u16* Qp = qws + hb;
  const u16* Kp = kws + hb;
  const u16* Vp = vws + hb;
  const int start = qhalf * 8;          // this wave's Q-tiles: [start, start+8); start % 4 == 0

  // 4-slot register rings (slot = jt & 3): K fragments (A-layout) and V fragments (B-layout)
  s16x8 klo[4] = {}, khi[4] = {};
  s16x8 vfr[4][4] = {};

#define LOADKV(jt, slot) do {                                                \
    const u16* _p = Kp + (jt) * 1024 + c15 * 64 + g * 8;                     \
    klo[slot] = *(const s16x8*)_p;                                           \
    khi[slot] = *(const s16x8*)(_p + 32);                                    \
    const int _rb = (jt) * 16 + ((g & 1) << 3);                              \
    _Pragma("unroll")                                                        \
    for (int _dt = 0; _dt < 4; ++_dt) {                                      \
      s16x8 _t;                                                              \
      _Pragma("unroll")                                                      \
      for (int _i = 0; _i < 8; ++_i)                                         \
        _t[_i] = (short)Vp[(_rb + _i) * 64 + _dt * 16 + c15];                \
      vfr[slot][_dt] = _t;                                                   \
    }                                                                        \
  } while (0)

  if (start >= 2) LOADKV(start - 2, 2);
  if (start >= 1) LOADKV(start - 1, 3);
  LOADKV(start, 0);

#pragma unroll
  for (int ii = 0; ii < 8; ++ii) {
    const int i16 = start + ii;
    const int sP = (ii + 1) & 3;
    const int s0 = ii & 3;
    const int s1 = (ii + 3) & 3;
    const int s2 = (ii + 2) & 3;
    if (ii < 7) LOADKV(i16 + 1, sP);   // prefetch next K/V tile

    const u16* qp = Qp + i16 * 1024 + c15 * 64 + g * 8;
    const s16x8 qf0 = *(const s16x8*)qp;
    const s16x8 qf1 = *(const s16x8*)(qp + 32);

    // S^T[j][q] = sum_d K[j][d] Q[q][d]; lane holds j = jt*16 + g*4 + r, q = c15
    f32x4 sT0 = {}, sT1 = {}, sT2 = {};
    sT0 = MFMA32(klo[s0], qf0, sT0);
    sT0 = MFMA32(khi[s0], qf1, sT0);
    if (i16 >= 1) { sT1 = MFMA32(klo[s1], qf0, sT1); sT1 = MFMA32(khi[s1], qf1, sT1); }
    if (i16 >= 2) { sT2 = MFMA32(klo[s2], qf0, sT2); sT2 = MFMA32(khi[s2], qf1, sT2); }

    const int qrow = i16 * 16 + c15;
    float e0[4], e1[4], e2[4];
    float vmax = -3.0e38f;
#pragma unroll
    for (int r = 0; r < 4; ++r) {
      int dd = qrow - (i16 * 16 + g * 4 + r);
      e0[r] = (dd >= 0 && dd <= 32) ? sT0[r] * 0.125f : -1.0e30f;
      vmax = fmaxf(vmax, e0[r]);
    }
    if (i16 >= 1) {
#pragma unroll
      for (int r = 0; r < 4; ++r) {           // dd in 1..31, always in band
        e1[r] = sT1[r] * 0.125f;
        vmax = fmaxf(vmax, e1[r]);
      }
    }
    if (i16 >= 2) {
#pragma unroll
      for (int r = 0; r < 4; ++r) {
        int dd = qrow - ((i16 - 2) * 16 + g * 4 + r);   // 17..47
        e2[r] = (dd <= 32) ? sT2[r] * 0.125f : -1.0e30f;
        vmax = fmaxf(vmax, e2[r]);
      }
    }
    vmax = fmaxf(vmax, __shfl_xor(vmax, 16));
    vmax = fmaxf(vmax, __shfl_xor(vmax, 32));
    float ssum = 0.0f;
#pragma unroll
    for (int r = 0; r < 4; ++r) { e0[r] = __expf(e0[r] - vmax); ssum += e0[r]; }
    if (i16 >= 1) {
#pragma unroll
      for (int r = 0; r < 4; ++r) { e1[r] = __expf(e1[r] - vmax); ssum += e1[r]; }
    }
    if (i16 >= 2) {
#pragma unroll
      for (int r = 0; r < 4; ++r) { e2[r] = __expf(e2[r] - vmax); ssum += e2[r]; }
    }
    ssum += __shfl_xor(ssum, 16);
    ssum += __shfl_xor(ssum, 32);
    const float inv = 1.0f / ssum;

    unsigned c0a = packbf(e0[0] * inv, e0[1] * inv), c0b = packbf(e0[2] * inv, e0[3] * inv);
    unsigned c1a = 0, c1b = 0, c2a = 0, c2b = 0;
    if (i16 >= 1) { c1a = packbf(e1[0] * inv, e1[1] * inv); c1b = packbf(e1[2] * inv, e1[3] * inv); }
    if (i16 >= 2) { c2a = packbf(e2[0] * inv, e2[1] * inv); c2b = packbf(e2[2] * inv, e2[3] * inv); }

    const int src0 = ((g & 1) << 5) + c15;
    const int src1 = src0 + 16;
    const bool alo = (g < 2);
#define MKFRAG(pa, ua, ub) do {                                             \
      int _t0 = __shfl((int)(ua), src0), _t1 = __shfl((int)(ub), src0);     \
      int _t2 = __shfl((int)(ua), src1), _t3 = __shfl((int)(ub), src1);     \
      i32x4 _ti = { alo ? _t0 : 0, alo ? _t1 : 0, alo ? _t2 : 0, alo ? _t3 : 0 }; \
      pa = *(s16x8*)&_ti;                                                   \
    } while (0)
    s16x8 pa0, pa1, pa2;
    MKFRAG(pa0, c0a, c0b);
    MKFRAG(pa1, c1a, c1b);
    MKFRAG(pa2, c2a, c2b);
#undef MKFRAG

    f32x4 oa[4] = {};
#pragma unroll
    for (int dt = 0; dt < 4; ++dt) {
      oa[dt] = MFMA32(pa0, vfr[s0][dt], oa[dt]);
      if (i16 >= 1) oa[dt] = MFMA32(pa1, vfr[s1][dt], oa[dt]);
      if (i16 >= 2) oa[dt] = MFMA32(pa2, vfr[s2][dt], oa[dt]);
    }

#pragma unroll
    for (int dt = 0; dt < 4; ++dt) {
#pragma unroll
      for (int r = 0; r < 4; ++r) {
        int row = i16 * 16 + g * 4 + r;
        unsigned addr = (unsigned)(row * 512 + head * 128 + dt * 32 + c15 * 2);
        addr ^= ((unsigned)(row & 7)) << 4;
        *(u16*)((char*)Osh + addr) = (u16)f2bf(oa[dt][r]);
      }
    }
  }
#undef LOADKV

  __syncthreads();

  s16x8 afr[2][8];
#pragma unroll
  for (int mt = 0; mt < 2; ++mt) {
#pragma unroll
    for (int ks = 0; ks < 8; ++ks) {
      int row = wid * 32 + mt * 16 + c15;
      unsigned addr = ((unsigned)(row * 512 + ks * 64 + g * 16)) ^ (((unsigned)(row & 7)) << 4);
      afr[mt][ks] = *(const s16x8*)((const char*)Osh + addr);
    }
  }
  const int wbase = win * 256;
  for (int nt = 0; nt < 16; ++nt) {
    s16x8 bfr[8];
#pragma unroll
    for (int ks = 0; ks < 8; ++ks)
      bfr[ks] = *(const s16x8*)(wprojT + (nt * 16 + c15) * 256 + ks * 32 + g * 8);
    const float bv = bias[nt * 16 + c15];
    f32x4 a0 = {bv, bv, bv, bv};
    f32x4 a1 = {bv, bv, bv, bv};
#pragma unroll
    for (int ks = 0; ks < 8; ++ks) {
      a0 = MFMA32(afr[0][ks], bfr[ks], a0);
      a1 = MFMA32(afr[1][ks], bfr[ks], a1);
    }
    const int m0 = wbase + wid * 32;
#pragma unroll
    for (int r = 0; r < 4; ++r) {
      out[(size_t)(m0 + g * 4 + r) * 256 + nt * 16 + c15] = a0[r];
      out[(size_t)(m0 + 16 + g * 4 + r) * 256 + nt * 16 + c15] = a1[r];
    }
  }
}

extern "C" void kernel_launch(void* const* d_in, const int* in_sizes, int n_in,
                              void* d_out, int out_size, void* d_ws, size_t ws_size,
                              hipStream_t stream) {
  (void)in_sizes; (void)n_in; (void)out_size;
  const float* x     = (const float*)d_in[0];
  const float* wqkv  = (const float*)d_in[1];
  const float* wproj = (const float*)d_in[2];
  const float* bias  = (const float*)d_in[3];
  float* out = (float*)d_out;
  char* ws = (char*)d_ws;

  const size_t wBytes = (size_t)768 * 256 * 2 + (size_t)256 * 256 * 2;  // 524288
  u16* wqkvT  = (u16*)ws;
  u16* wprojT = (u16*)(ws + (size_t)768 * 256 * 2);
  u16* qkvbuf = (u16*)(ws + wBytes);

  const size_t perWin = 393216;        // 3 * 256 * 256 * 2 B
  size_t avail = (ws_size > wBytes) ? (ws_size - wBytes) : 0;
  int cwMax = (int)(avail / perWin);
  if (cwMax < 1) return;
  if (cwMax > 256) cwMax = 256;
  if (cwMax >= 4) cwMax &= ~3;         // keep nmTiles % 8 == 0 for the XCD mapping

  k_prep<<<1024, 256, 0, stream>>>(wqkv, wproj, wqkvT, wprojT);

  for (int w0 = 0; w0 < 256; w0 += cwMax) {
    int cw = 256 - w0 < cwMax ? 256 - w0 : cwMax;
    int whichStride = cw * 65536;
    int nm = cw * 2;                   // 128-row M-tiles
    k_qkv<<<nm * 6, 256, 0, stream>>>(x + (size_t)w0 * 65536, wqkvT, qkvbuf, whichStride, nm);
    k_attn_proj<<<cw, 512, 0, stream>>>(qkvbuf,
                                        qkvbuf + (size_t)whichStride,
                                        qkvbuf + (size_t)2 * whichStride,
                                        wprojT, bias,
                                        out + (size_t)w0 * 65536);
  }
}